// Round 9
// baseline (151.573 us; speedup 1.0000x reference)
//
#include <hip/hip_runtime.h>
#include <hip/hip_bf16.h>

// Joint network: out[b,t,u,o] = tanh(enc_proj[b,t,:] + dec_proj[b,u,:] + b1) @ W2 + b2
// B=8 T=256 U=64 D=512 H=1024 O=128.  All I/O fp32.
//
// tanh identity: with C2L = 2*log2(e),
//   tanh(x) = 1 - 2/(2^(C2L*x) + 1),  2^(C2L*(e+d+b1)) = Ep * Dp
// Ep/Dp precomputed fp16 in the projection epilogue.
// R8 constant-column identity: out = c + b2 - 2*(r @ W2) where
//   r = 1/(min(Ep*Dp + 1, 126)),  c[o] = sum_h W2[h,o]  (precomputed f32).
//
// ws: W1T f16 [1024][1024] @0 (2MiB) | W2T f16 [128][1024] @2MiB (256KiB)
//     Ep f16 [2048][1024] @2.25MiB (4MiB) | Dp f16 [512][1024] @6.25MiB (1MiB)
//     Csum f32 [128] @7.25MiB

typedef _Float16 f16x8 __attribute__((ext_vector_type(8)));
typedef _Float16 f16x2 __attribute__((ext_vector_type(2)));
typedef float    f32x4 __attribute__((ext_vector_type(4)));

#define C2L 2.8853900817779268f

__device__ __forceinline__ float fast_exp2(float x) { return __builtin_amdgcn_exp2f(x); }

// v_cvt_pkrtz_f16_f32 returns __fp16x2 — bitcast to our _Float16x2
__device__ __forceinline__ f16x2 pk_cvt(float x, float y) {
    auto r = __builtin_amdgcn_cvt_pkrtz(x, y);
    union { decltype(r) a; f16x2 b; } c; c.a = r; return c.b;
}

// r = 1/(e*d + 1) on 8 packed f16 via pairwise reciprocal (4 rcph per 8).
// p capped at 126 so q = p0*p1 <= 15876 keeps rq = rcph(q) >= 6.3e-5 in the
// f16 normal range. The "1-2r" of tanh lives in the epilogue (Csum identity).
__device__ __forceinline__ f16x8 recip8(f16x8 e, f16x8 d) {
    const f16x8 one = {1,1,1,1,1,1,1,1};
    const f16x8 cap = {126,126,126,126,126,126,126,126};
    union { f16x8 v; _Float16 s[8]; } p, r;
    p.v = e * d + one;                              // v_pk_fma_f16 x4
    p.v = __builtin_elementwise_min(p.v, cap);      // v_pk_min_f16 x4
    #pragma unroll
    for (int i = 0; i < 4; ++i) {
        _Float16 q  = p.s[2*i] * p.s[2*i+1];
        _Float16 rq = __builtin_amdgcn_rcph(q);
        r.s[2*i]   = p.s[2*i+1] * rq;               // = 1/p0
        r.s[2*i+1] = p.s[2*i]   * rq;               // = 1/p1
    }
    return r.v;
}

// async 16B global -> LDS (LDS dest is wave-uniform base + lane*16)
__device__ __forceinline__ void stage16(const void* g, void* l) {
    __builtin_amdgcn_global_load_lds(
        (const __attribute__((address_space(1))) unsigned int*)g,
        (__attribute__((address_space(3))) unsigned int*)l, 16, 0, 0);
}

// ---------------------------------------------------------------- transpose (+ column sums)
// bx<32: W1 (1024x1024) -> W1T ; 32<=bx<36: W2 (1024x128) -> W2T
// bx==36, by==0: Csum[o] = sum_k W2[k][o].
__global__ __launch_bounds__(1024) void transpose_both(
    const float* __restrict__ W1, const float* __restrict__ W2,
    _Float16* __restrict__ W1T, _Float16* __restrict__ W2T,
    float* __restrict__ Csum)
{
    __shared__ float tile[32][33];
    __shared__ float part[8][128];
    int bx = blockIdx.x;
    int tx = threadIdx.x, ty = threadIdx.y;
    if (bx == 36) {
        if (blockIdx.y) return;
        int t = ty * 32 + tx;            // 0..1023
        int o = t & 127, kg = t >> 7;    // 8 k-groups x 128 cols
        float s = 0.f;
        #pragma unroll 8
        for (int k = kg; k < 1024; k += 8) s += W2[k * 128 + o];
        part[kg][o] = s;
        __syncthreads();
        if (t < 128) {
            float tot = 0.f;
            #pragma unroll
            for (int g = 0; g < 8; ++g) tot += part[g][t];
            Csum[t] = tot;
        }
        return;
    }
    const float* src; _Float16* dst; int C, c0;
    if (bx < 32) { src = W1; dst = W1T; C = 1024; c0 = bx * 32; }
    else         { src = W2; dst = W2T; C = 128;  c0 = (bx - 32) * 32; }
    int r0 = blockIdx.y * 32;
    tile[ty][tx] = src[(r0 + ty) * C + (c0 + tx)];
    __syncthreads();
    dst[(size_t)(c0 + ty) * 1024 + (r0 + tx)] = (_Float16)tile[tx][ty];
}

// ---------------------------------------------------------------- projections
// rows 0..2047 -> Ep = 2^(C2L*(enc@W1[:512] + b1)); rows 2048.. -> Dp (dec, no bias)
// v3 structure (kept, −20 us total in R4) + launch_bounds(256,4) (R7, kept).
__global__ __launch_bounds__(256, 4) void proj_exp(
    const float* __restrict__ enc,     // [2048][512]
    const float* __restrict__ dec,     // [512][512]
    const _Float16* __restrict__ W1T,  // [1024][1024]
    const float* __restrict__ b1,      // [1024]
    _Float16* __restrict__ Ep,         // [2048][1024]
    _Float16* __restrict__ Dp)         // [512][1024]
{
    __shared__ _Float16 sB[2][64 * 64];   // 2 x 8 KiB: [n-col][k] swizzled

    const int K = 512;
    int tid  = threadIdx.x;
    int w    = tid >> 6, lane = tid & 63;
    int quad = lane >> 4, l15 = lane & 15;
    int m_base = blockIdx.y * 64;
    int n_base = blockIdx.x * 64;

    bool is_enc = (m_base < 2048);          // block-uniform (boundary 2048 = 32*64)
    int row = m_base + w * 16 + l15;
    const float* A = is_enc ? (enc + (size_t)row * K)
                            : (dec + (size_t)(row - 2048) * K);
    const _Float16* Bsrc = W1T + (is_enc ? 0 : 512);

    f32x4 acc[4] = {};

    // stage B tile 0 (64 cols x 64 k f16 = 8 KiB): 512 chunks of 16B, 2/thread
    #pragma unroll
    for (int i = 0; i < 2; ++i) {
        int c = i * 256 + tid;
        int r = c >> 3, kcs = c & 7;
        stage16(Bsrc + (size_t)(n_base + r) * 1024 + ((kcs ^ (r & 7)) << 3),
                &sB[0][(i * 256 + (tid & 0xC0)) * 8]);
    }
    // A prefetch for tile 0: lane's 16 floats at k = quad*8 (+32)
    float4 a0lo = *reinterpret_cast<const float4*>(A + quad * 8);
    float4 a0hi = *reinterpret_cast<const float4*>(A + quad * 8 + 4);
    float4 a1lo = *reinterpret_cast<const float4*>(A + 32 + quad * 8);
    float4 a1hi = *reinterpret_cast<const float4*>(A + 32 + quad * 8 + 4);

    for (int it = 0; it < 8; ++it) {
        __syncthreads();   // drains stage(it) — issued one full tile ago
        float4 n0lo, n0hi, n1lo, n1hi;
        if (it < 7) {
            int kb = (it + 1) * 64;
            _Float16* dst = sB[(it + 1) & 1];
            #pragma unroll
            for (int i = 0; i < 2; ++i) {
                int c = i * 256 + tid;
                int r = c >> 3, kcs = c & 7;
                stage16(Bsrc + (size_t)(n_base + r) * 1024 + kb + ((kcs ^ (r & 7)) << 3),
                        dst + (i * 256 + (tid & 0xC0)) * 8);
            }
            n0lo = *reinterpret_cast<const float4*>(A + kb + quad * 8);
            n0hi = *reinterpret_cast<const float4*>(A + kb + quad * 8 + 4);
            n1lo = *reinterpret_cast<const float4*>(A + kb + 32 + quad * 8);
            n1hi = *reinterpret_cast<const float4*>(A + kb + 32 + quad * 8 + 4);
        }
        const _Float16* sb = sB[it & 1];
        // ki2 = 0
        {
            union { f16x8 v; f16x2 h[4]; } a;
            a.h[0] = pk_cvt(a0lo.x, a0lo.y);
            a.h[1] = pk_cvt(a0lo.z, a0lo.w);
            a.h[2] = pk_cvt(a0hi.x, a0hi.y);
            a.h[3] = pk_cvt(a0hi.z, a0hi.w);
            int sw = ((0 * 4 + quad) ^ (l15 & 7)) << 3;
            #pragma unroll
            for (int f = 0; f < 4; ++f) {
                f16x8 bb = *reinterpret_cast<const f16x8*>(sb + (f * 16 + l15) * 64 + sw);
                acc[f] = __builtin_amdgcn_mfma_f32_16x16x32_f16(a.v, bb, acc[f], 0, 0, 0);
            }
        }
        // ki2 = 1
        {
            union { f16x8 v; f16x2 h[4]; } a;
            a.h[0] = pk_cvt(a1lo.x, a1lo.y);
            a.h[1] = pk_cvt(a1lo.z, a1lo.w);
            a.h[2] = pk_cvt(a1hi.x, a1hi.y);
            a.h[3] = pk_cvt(a1hi.z, a1hi.w);
            int sw = ((1 * 4 + quad) ^ (l15 & 7)) << 3;
            #pragma unroll
            for (int f = 0; f < 4; ++f) {
                f16x8 bb = *reinterpret_cast<const f16x8*>(sb + (f * 16 + l15) * 64 + sw);
                acc[f] = __builtin_amdgcn_mfma_f32_16x16x32_f16(a.v, bb, acc[f], 0, 0, 0);
            }
        }
        a0lo = n0lo; a0hi = n0hi; a1lo = n1lo; a1hi = n1hi;
    }

    #pragma unroll
    for (int f = 0; f < 4; ++f) {
        int col = n_base + f * 16 + l15;
        float bv = is_enc ? b1[col] : 0.0f;
        #pragma unroll
        for (int v = 0; v < 4; ++v) {
            int orow = m_base + w * 16 + quad * 4 + v;
            float val = fast_exp2(C2L * (acc[f][v] + bv));
            if (is_enc) Ep[(size_t)orow * 1024 + col] = (_Float16)val;
            else        Dp[(size_t)(orow - 2048) * 1024 + col] = (_Float16)val;
        }
    }
}

// ---------------------------------------------------------------- main fused
// v9: the two formerly co-resident 256-thread blocks merged into ONE
// 512-thread block (8 t-rows, grid 256 = exactly 1 block/CU).
// Wave = (t-quad tq, u-quarter uq): per-wave shape IDENTICAL to the proven
// R4 kernel (4t x 16u x 128o, acc 128 AGPR, 16 bb ds_reads/tile — no extra
// LDS traffic, avoiding R6's mistake). Gains vs R4: W2T k-tile staged ONCE
// per CU per tile (was twice: -1024 global_load_lds chunks, -16KB LDS
// writes/tile); residency guaranteed (8 waves, 48KB LDS, 2x252 reg <= 512
// per SIMD) — R4's occupancy counter (16% = ~5 waves/CU < the nominal 8)
// suggested the 2nd block was often not co-resident. Refuted alternatives:
// Dp staging (R2), no-LDS W2T (R5), 8-wave split-u (R6), k-phase rot (R7).
__global__ __launch_bounds__(512, 2) void joint_main(
    const _Float16* __restrict__ Ep,   // [2048][1024]
    const _Float16* __restrict__ Dp,   // [512][1024]
    const _Float16* __restrict__ W2T,  // [128][1024]
    const float* __restrict__ b2,      // [128]
    const float* __restrict__ Csum,    // [128]
    float* __restrict__ out)           // [8][256][64][128]
{
    __shared__ _Float16 sB[2][128 * 64];   // 2 x 16 KiB
    __shared__ _Float16 sE[8 * 1024];      // 16 KiB: 8 Ep rows

    int t0 = blockIdx.x * 8, b = blockIdx.y;
    int tid  = threadIdx.x;
    int w    = tid >> 6, lane = tid & 63;
    int quad = lane >> 4, l15 = lane & 15;
    int uq   = w & 3, tq = w >> 2;
    int u0   = uq * 16;

    const _Float16* epB = Ep + (size_t)(b * 256 + t0) * 1024;   // 8 contiguous rows
    const _Float16* dpr = Dp + (size_t)(b * 64 + u0 + l15) * 1024;

    f32x4 acc[4][8] = {};   // [t-within-quad][o-tile] = 128 AGPRs

    // stage 8 Ep rows (16 KiB, linear both sides): 1024 chunks, 2 per thread
    #pragma unroll
    for (int i = 0; i < 2; ++i) {
        int c = i * 512 + tid;
        stage16(epB + c * 8, sE + (i * 512 + (tid & 0x1C0)) * 8);
    }
    // stage W2T tile 0 into buf 0 (1024 chunks of 16B, 2 per thread)
    #pragma unroll
    for (int i = 0; i < 2; ++i) {
        int c = i * 512 + tid;
        int row = c >> 3, kcs = c & 7;
        stage16(W2T + row * 1024 + ((kcs ^ (row & 7)) << 3),
                &sB[0][(i * 512 + (tid & 0x1C0)) * 8]);
    }

    for (int it = 0; it < 16; ++it) {
        __syncthreads();   // drains stage(it) — issued one full tile ago (and sE at it=0)
        if (it < 15) {
            int kb = (it + 1) * 64;
            _Float16* dst = sB[(it + 1) & 1];
            #pragma unroll
            for (int i = 0; i < 2; ++i) {
                int c = i * 512 + tid;
                int row = c >> 3, kcs = c & 7;
                stage16(W2T + row * 1024 + kb + ((kcs ^ (row & 7)) << 3),
                        dst + (i * 512 + (tid & 0x1C0)) * 8);
            }
        }
        const _Float16* sb = sB[it & 1];
        #pragma unroll
        for (int ki2 = 0; ki2 < 2; ++ki2) {
            int k = it * 64 + ki2 * 32 + quad * 8;
            f16x8 d8 = *reinterpret_cast<const f16x8*>(dpr + k);
            f16x8 A[4];
            #pragma unroll
            for (int tt = 0; tt < 4; ++tt) {
                // broadcast ds_read_b128 (same addr per quad group): conflict-free
                f16x8 e = *reinterpret_cast<const f16x8*>(sE + (tq * 4 + tt) * 1024 + k);
                A[tt] = recip8(e, d8);
            }
            int kc3 = ki2 * 4 + quad;
            int sw  = (kc3 ^ (l15 & 7)) << 3;        // uniform across f
            #pragma unroll
            for (int f = 0; f < 8; ++f) {
                f16x8 bb = *reinterpret_cast<const f16x8*>(
                    sb + (f * 16 + l15) * 64 + sw);
                #pragma unroll
                for (int tt = 0; tt < 4; ++tt)
                    acc[tt][f] = __builtin_amdgcn_mfma_f32_16x16x32_f16(A[tt], bb, acc[tt][f], 0, 0, 0);
            }
        }
    }

    #pragma unroll
    for (int tt = 0; tt < 4; ++tt) {
        float* o = out + (size_t)(b * 256 + t0 + tq * 4 + tt) * 64 * 128;
        #pragma unroll
        for (int f = 0; f < 8; ++f) {
            int oc = f * 16 + l15;
            float bv = Csum[oc] + b2[oc];
            #pragma unroll
            for (int v = 0; v < 4; ++v) {
                int u = u0 + quad * 4 + v;
                o[u * 128 + oc] = fmaf(-2.0f, acc[tt][f][v], bv);
            }
        }
    }
}

// ---------------------------------------------------------------- launch
extern "C" void kernel_launch(void* const* d_in, const int* in_sizes, int n_in,
                              void* d_out, int out_size, void* d_ws, size_t ws_size,
                              hipStream_t stream) {
    const float* enc = (const float*)d_in[0]; // [8][256][512]
    const float* dec = (const float*)d_in[1]; // [8][64][512]
    const float* W1  = (const float*)d_in[2]; // [1024][1024]
    const float* b1  = (const float*)d_in[3]; // [1024]
    const float* W2  = (const float*)d_in[4]; // [1024][128]
    const float* b2  = (const float*)d_in[5]; // [128]
    float* out = (float*)d_out;

    char* ws = (char*)d_ws;
    _Float16* W1T = (_Float16*)(ws);                               // 2 MiB
    _Float16* W2T = (_Float16*)(ws + (2u << 20));                  // 256 KiB
    _Float16* EpP = (_Float16*)(ws + (2u << 20) + (256u << 10));   // 4 MiB
    _Float16* DpP = (_Float16*)(ws + (6u << 20) + (256u << 10));   // 1 MiB
    float*    Csm = (float*)   (ws + (7u << 20) + (256u << 10));   // 512 B

    transpose_both<<<dim3(37, 32), dim3(32, 32), 0, stream>>>(W1, W2, W1T, W2T, Csm);

    // fused projections + exp2 epilogue: M = 2048 (enc) + 512 (dec)
    proj_exp<<<dim3(16, 40), 256, 0, stream>>>(enc, dec, W1T, b1, EpP, DpP);

    // v9: 512-thread blocks (8t each), grid 256 = 1 block/CU
    joint_main<<<dim3(32, 8), 512, 0, stream>>>(EpP, DpP, W2T, b2, Csm, out);
}

// Round 10
// 147.077 us; speedup vs baseline: 1.0306x; 1.0306x over previous
//
#include <hip/hip_runtime.h>
#include <hip/hip_bf16.h>

// Joint network: out[b,t,u,o] = tanh(enc_proj[b,t,:] + dec_proj[b,u,:] + b1) @ W2 + b2
// B=8 T=256 U=64 D=512 H=1024 O=128.  All I/O fp32.
//
// tanh identity: with C2L = 2*log2(e),
//   tanh(x) = 1 - 2/(2^(C2L*x) + 1),  2^(C2L*(e+d+b1)) = Ep * Dp
// Ep/Dp precomputed fp16 in the projection epilogue.
// Constant-column identity (R8): out = c + b2 - 2*(r @ W2) where
//   r = 1/(min(Ep*Dp + 1, 126)),  c[o] = sum_h W2[h,o]  (precomputed f32).
//
// ws: W1T f16 [1024][1024] @0 (2MiB) | W2T f16 [128][1024] @2MiB (256KiB)
//     Ep f16 [2048][1024] @2.25MiB (4MiB) | Dp f16 [512][1024] @6.25MiB (1MiB)
//     Csum f32 [128] @7.25MiB

typedef _Float16 f16x8 __attribute__((ext_vector_type(8)));
typedef _Float16 f16x2 __attribute__((ext_vector_type(2)));
typedef float    f32x4 __attribute__((ext_vector_type(4)));

#define C2L 2.8853900817779268f

__device__ __forceinline__ float fast_exp2(float x) { return __builtin_amdgcn_exp2f(x); }

// v_cvt_pkrtz_f16_f32 returns __fp16x2 — bitcast to our _Float16x2
__device__ __forceinline__ f16x2 pk_cvt(float x, float y) {
    auto r = __builtin_amdgcn_cvt_pkrtz(x, y);
    union { decltype(r) a; f16x2 b; } c; c.a = r; return c.b;
}

// r = 1/(e*d + 1) on 8 packed f16 via pairwise reciprocal (4 rcph per 8).
// p capped at 126 so q = p0*p1 <= 15876 keeps rq = rcph(q) >= 6.3e-5 in the
// f16 normal range. The "1-2r" of tanh lives in the epilogue (Csum identity).
__device__ __forceinline__ f16x8 recip8(f16x8 e, f16x8 d) {
    const f16x8 one = {1,1,1,1,1,1,1,1};
    const f16x8 cap = {126,126,126,126,126,126,126,126};
    union { f16x8 v; _Float16 s[8]; } p, r;
    p.v = e * d + one;                              // v_pk_fma_f16 x4
    p.v = __builtin_elementwise_min(p.v, cap);      // v_pk_min_f16 x4
    #pragma unroll
    for (int i = 0; i < 4; ++i) {
        _Float16 q  = p.s[2*i] * p.s[2*i+1];
        _Float16 rq = __builtin_amdgcn_rcph(q);
        r.s[2*i]   = p.s[2*i+1] * rq;               // = 1/p0
        r.s[2*i+1] = p.s[2*i]   * rq;               // = 1/p1
    }
    return r.v;
}

// async 16B global -> LDS (LDS dest is wave-uniform base + lane*16)
__device__ __forceinline__ void stage16(const void* g, void* l) {
    __builtin_amdgcn_global_load_lds(
        (const __attribute__((address_space(1))) unsigned int*)g,
        (__attribute__((address_space(3))) unsigned int*)l, 16, 0, 0);
}

// ---------------------------------------------------------------- transpose (+ column sums)
// bx<32: W1 (1024x1024) -> W1T ; 32<=bx<36: W2 (1024x128) -> W2T
// bx==36, by==0: Csum[o] = sum_k W2[k][o].
__global__ __launch_bounds__(1024) void transpose_both(
    const float* __restrict__ W1, const float* __restrict__ W2,
    _Float16* __restrict__ W1T, _Float16* __restrict__ W2T,
    float* __restrict__ Csum)
{
    __shared__ float tile[32][33];
    __shared__ float part[8][128];
    int bx = blockIdx.x;
    int tx = threadIdx.x, ty = threadIdx.y;
    if (bx == 36) {
        if (blockIdx.y) return;
        int t = ty * 32 + tx;            // 0..1023
        int o = t & 127, kg = t >> 7;    // 8 k-groups x 128 cols
        float s = 0.f;
        #pragma unroll 8
        for (int k = kg; k < 1024; k += 8) s += W2[k * 128 + o];
        part[kg][o] = s;
        __syncthreads();
        if (t < 128) {
            float tot = 0.f;
            #pragma unroll
            for (int g = 0; g < 8; ++g) tot += part[g][t];
            Csum[t] = tot;
        }
        return;
    }
    const float* src; _Float16* dst; int C, c0;
    if (bx < 32) { src = W1; dst = W1T; C = 1024; c0 = bx * 32; }
    else         { src = W2; dst = W2T; C = 128;  c0 = (bx - 32) * 32; }
    int r0 = blockIdx.y * 32;
    tile[ty][tx] = src[(r0 + ty) * C + (c0 + tx)];
    __syncthreads();
    dst[(size_t)(c0 + ty) * 1024 + (r0 + tx)] = (_Float16)tile[tx][ty];
}

// ---------------------------------------------------------------- projections
// rows 0..2047 -> Ep = 2^(C2L*(enc@W1[:512] + b1)); rows 2048.. -> Dp (dec, no bias)
// v4: n-tile 64 -> 32 (grid x 16 -> 32): 1280 blocks = 5 blocks/CU (was 2.5).
// proj is latency-bound; the v3 staged structure is kept verbatim, per-block
// work halves, TLP doubles. acc 2 x f32x4. B-panel stage = 4 KiB/tile.
__global__ __launch_bounds__(256, 4) void proj_exp(
    const float* __restrict__ enc,     // [2048][512]
    const float* __restrict__ dec,     // [512][512]
    const _Float16* __restrict__ W1T,  // [1024][1024]
    const float* __restrict__ b1,      // [1024]
    _Float16* __restrict__ Ep,         // [2048][1024]
    _Float16* __restrict__ Dp)         // [512][1024]
{
    __shared__ _Float16 sB[2][32 * 64];   // 2 x 4 KiB: [n-col][k] swizzled

    const int K = 512;
    int tid  = threadIdx.x;
    int w    = tid >> 6, lane = tid & 63;
    int quad = lane >> 4, l15 = lane & 15;
    int m_base = blockIdx.y * 64;
    int n_base = blockIdx.x * 32;

    bool is_enc = (m_base < 2048);          // block-uniform (boundary 2048 = 32*64)
    int row = m_base + w * 16 + l15;
    const float* A = is_enc ? (enc + (size_t)row * K)
                            : (dec + (size_t)(row - 2048) * K);
    const _Float16* Bsrc = W1T + (is_enc ? 0 : 512);

    f32x4 acc[2] = {};

    // stage B tile 0 (32 cols x 64 k f16 = 4 KiB): 256 chunks of 16B, 1/thread
    {
        int r = tid >> 3, kcs = tid & 7;
        stage16(Bsrc + (size_t)(n_base + r) * 1024 + ((kcs ^ (r & 7)) << 3),
                &sB[0][(tid & 0xC0) * 8]);
    }
    // A prefetch for tile 0: lane's 16 floats at k = quad*8 (+32)
    float4 a0lo = *reinterpret_cast<const float4*>(A + quad * 8);
    float4 a0hi = *reinterpret_cast<const float4*>(A + quad * 8 + 4);
    float4 a1lo = *reinterpret_cast<const float4*>(A + 32 + quad * 8);
    float4 a1hi = *reinterpret_cast<const float4*>(A + 32 + quad * 8 + 4);

    for (int it = 0; it < 8; ++it) {
        __syncthreads();   // drains stage(it) — issued one full tile ago
        float4 n0lo, n0hi, n1lo, n1hi;
        if (it < 7) {
            int kb = (it + 1) * 64;
            int r = tid >> 3, kcs = tid & 7;
            stage16(Bsrc + (size_t)(n_base + r) * 1024 + kb + ((kcs ^ (r & 7)) << 3),
                    sB[(it + 1) & 1] + (tid & 0xC0) * 8);
            n0lo = *reinterpret_cast<const float4*>(A + kb + quad * 8);
            n0hi = *reinterpret_cast<const float4*>(A + kb + quad * 8 + 4);
            n1lo = *reinterpret_cast<const float4*>(A + kb + 32 + quad * 8);
            n1hi = *reinterpret_cast<const float4*>(A + kb + 32 + quad * 8 + 4);
        }
        const _Float16* sb = sB[it & 1];
        // ki2 = 0
        {
            union { f16x8 v; f16x2 h[4]; } a;
            a.h[0] = pk_cvt(a0lo.x, a0lo.y);
            a.h[1] = pk_cvt(a0lo.z, a0lo.w);
            a.h[2] = pk_cvt(a0hi.x, a0hi.y);
            a.h[3] = pk_cvt(a0hi.z, a0hi.w);
            int sw = ((0 * 4 + quad) ^ (l15 & 7)) << 3;
            #pragma unroll
            for (int f = 0; f < 2; ++f) {
                f16x8 bb = *reinterpret_cast<const f16x8*>(sb + (f * 16 + l15) * 64 + sw);
                acc[f] = __builtin_amdgcn_mfma_f32_16x16x32_f16(a.v, bb, acc[f], 0, 0, 0);
            }
        }
        // ki2 = 1
        {
            union { f16x8 v; f16x2 h[4]; } a;
            a.h[0] = pk_cvt(a1lo.x, a1lo.y);
            a.h[1] = pk_cvt(a1lo.z, a1lo.w);
            a.h[2] = pk_cvt(a1hi.x, a1hi.y);
            a.h[3] = pk_cvt(a1hi.z, a1hi.w);
            int sw = ((1 * 4 + quad) ^ (l15 & 7)) << 3;
            #pragma unroll
            for (int f = 0; f < 2; ++f) {
                f16x8 bb = *reinterpret_cast<const f16x8*>(sb + (f * 16 + l15) * 64 + sw);
                acc[f] = __builtin_amdgcn_mfma_f32_16x16x32_f16(a.v, bb, acc[f], 0, 0, 0);
            }
        }
        a0lo = n0lo; a0hi = n0hi; a1lo = n1lo; a1hi = n1hi;
    }

    #pragma unroll
    for (int f = 0; f < 2; ++f) {
        int col = n_base + f * 16 + l15;
        float bv = is_enc ? b1[col] : 0.0f;
        #pragma unroll
        for (int v = 0; v < 4; ++v) {
            int orow = m_base + w * 16 + quad * 4 + v;
            float val = fast_exp2(C2L * (acc[f][v] + bv));
            if (is_enc) Ep[(size_t)orow * 1024 + col] = (_Float16)val;
            else        Dp[(size_t)(orow - 2048) * 1024 + col] = (_Float16)val;
        }
    }
}

// ---------------------------------------------------------------- main fused
// R8 base (best measured, 47.8 us): block = 4t x 64u x 128o, 4 waves, wave w
// owns u-rows [16w,16w+16) for all 4t; 2 independent in-phase blocks/CU
// (R5/R6/R7/R9 all refuted departures from this). W2T LDS-staged, Ep staged
// once, Dp direct global, Csum identity epilogue.
// v10: BK 64 -> 128. Halves barrier-sync events (16 -> 8 per block; ~45% of
// wall was inter-wave sync jitter at barriers); per-phase compute doubles
// (4 d8 loads issued up front -> deeper ILP vs L2 latency). Staging traffic,
// LDS read volume, swizzle structure, per-ki2 register working set all
// unchanged (#pragma unroll 2 pins the proven 2-deep schedule).
// LDS: 2 x 32 KiB sB + 8 KiB sE = 72 KiB; 2 blocks/CU = 144 <= 160 KiB.
__global__ __launch_bounds__(256, 2) void joint_main(
    const _Float16* __restrict__ Ep,   // [2048][1024]
    const _Float16* __restrict__ Dp,   // [512][1024]
    const _Float16* __restrict__ W2T,  // [128][1024]
    const float* __restrict__ b2,      // [128]
    const float* __restrict__ Csum,    // [128]
    float* __restrict__ out)           // [8][256][64][128]
{
    __shared__ _Float16 sB[2][128 * 128];  // 2 x 32 KiB
    __shared__ _Float16 sE[4 * 1024];      // 8 KiB: 4 Ep rows

    int t0 = blockIdx.x * 4, b = blockIdx.y;
    int tid  = threadIdx.x;
    int w    = tid >> 6, lane = tid & 63;
    int quad = lane >> 4, l15 = lane & 15;
    int u0   = w * 16;

    const _Float16* epB = Ep + (size_t)(b * 256 + t0) * 1024;   // 4 contiguous rows
    const _Float16* dpr = Dp + (size_t)(b * 64 + u0 + l15) * 1024;

    f32x4 acc[4][8] = {};   // [t][o-tile] = 128 AGPRs

    // stage 4 Ep rows (8 KiB, linear both sides): 512 chunks, 2 per thread
    #pragma unroll
    for (int i = 0; i < 2; ++i) {
        int c = i * 256 + tid;
        stage16(epB + c * 8, sE + (i * 256 + (tid & 0xC0)) * 8);
    }
    // stage W2T super-tile 0 (128 rows x 128 k = 32 KiB): 2048 chunks, 8/thread
    #pragma unroll
    for (int i = 0; i < 8; ++i) {
        int c = i * 256 + tid;
        int row = c >> 4, kcs = c & 15;
        stage16(W2T + row * 1024 + ((kcs ^ (row & 7)) << 3),
                &sB[0][(i * 256 + (tid & 0xC0)) * 8]);
    }

    for (int it = 0; it < 8; ++it) {
        __syncthreads();   // drains stage(it) — issued one full super-tile ago
        if (it < 7) {
            int kb = (it + 1) * 128;
            _Float16* dst = sB[(it + 1) & 1];
            #pragma unroll
            for (int i = 0; i < 8; ++i) {
                int c = i * 256 + tid;
                int row = c >> 4, kcs = c & 15;
                stage16(W2T + row * 1024 + kb + ((kcs ^ (row & 7)) << 3),
                        dst + (i * 256 + (tid & 0xC0)) * 8);
            }
        }
        const _Float16* sb = sB[it & 1];
        #pragma unroll 2
        for (int ki2 = 0; ki2 < 4; ++ki2) {
            int k = it * 128 + ki2 * 32 + quad * 8;
            f16x8 d8 = *reinterpret_cast<const f16x8*>(dpr + k);
            f16x8 A[4];
            #pragma unroll
            for (int tt = 0; tt < 4; ++tt) {
                // broadcast ds_read_b128 (same addr per quad group): conflict-free
                f16x8 e = *reinterpret_cast<const f16x8*>(sE + tt * 1024 + k);
                A[tt] = recip8(e, d8);
            }
            int kc3 = ki2 * 4 + quad;               // 0..15
            int sw  = (kc3 ^ (l15 & 7)) << 3;       // uniform across f
            #pragma unroll
            for (int f = 0; f < 8; ++f) {
                f16x8 bb = *reinterpret_cast<const f16x8*>(
                    sb + (f * 16 + l15) * 128 + sw);
                #pragma unroll
                for (int tt = 0; tt < 4; ++tt)
                    acc[tt][f] = __builtin_amdgcn_mfma_f32_16x16x32_f16(A[tt], bb, acc[tt][f], 0, 0, 0);
            }
        }
    }

    #pragma unroll
    for (int tt = 0; tt < 4; ++tt) {
        float* o = out + (size_t)(b * 256 + t0 + tt) * 64 * 128;
        #pragma unroll
        for (int f = 0; f < 8; ++f) {
            int oc = f * 16 + l15;
            float bv = Csum[oc] + b2[oc];
            #pragma unroll
            for (int v = 0; v < 4; ++v) {
                int u = u0 + quad * 4 + v;
                o[u * 128 + oc] = fmaf(-2.0f, acc[tt][f][v], bv);
            }
        }
    }
}

// ---------------------------------------------------------------- launch
extern "C" void kernel_launch(void* const* d_in, const int* in_sizes, int n_in,
                              void* d_out, int out_size, void* d_ws, size_t ws_size,
                              hipStream_t stream) {
    const float* enc = (const float*)d_in[0]; // [8][256][512]
    const float* dec = (const float*)d_in[1]; // [8][64][512]
    const float* W1  = (const float*)d_in[2]; // [1024][1024]
    const float* b1  = (const float*)d_in[3]; // [1024]
    const float* W2  = (const float*)d_in[4]; // [1024][128]
    const float* b2  = (const float*)d_in[5]; // [128]
    float* out = (float*)d_out;

    char* ws = (char*)d_ws;
    _Float16* W1T = (_Float16*)(ws);                               // 2 MiB
    _Float16* W2T = (_Float16*)(ws + (2u << 20));                  // 256 KiB
    _Float16* EpP = (_Float16*)(ws + (2u << 20) + (256u << 10));   // 4 MiB
    _Float16* DpP = (_Float16*)(ws + (6u << 20) + (256u << 10));   // 1 MiB
    float*    Csm = (float*)   (ws + (7u << 20) + (256u << 10));   // 512 B

    transpose_both<<<dim3(37, 32), dim3(32, 32), 0, stream>>>(W1, W2, W1T, W2T, Csm);

    // fused projections + exp2 epilogue: M = 2048 (enc) + 512 (dec)
    // v4: 32-col n-tiles -> 1280 blocks (5 blocks/CU)
    proj_exp<<<dim3(32, 40), 256, 0, stream>>>(enc, dec, W1T, b1, EpP, DpP);

    joint_main<<<dim3(64, 8), 256, 0, stream>>>(EpP, DpP, W2T, b2, Csm, out);
}

// Round 11
// 141.825 us; speedup vs baseline: 1.0687x; 1.0370x over previous
//
#include <hip/hip_runtime.h>
#include <hip/hip_bf16.h>

// Joint network: out[b,t,u,o] = tanh(enc_proj[b,t,:] + dec_proj[b,u,:] + b1) @ W2 + b2
// B=8 T=256 U=64 D=512 H=1024 O=128.  All I/O fp32.
//
// tanh identity: with C2L = 2*log2(e),
//   tanh(x) = 1 - 2/(2^(C2L*x) + 1),  2^(C2L*(e+d+b1)) = Ep * Dp
// Ep/Dp precomputed fp16 in the projection epilogue.
// Constant-column identity (R8): out = c + b2 - 2*(r @ W2) where
//   r = 1/(min(Ep*Dp + 1, 126)),  c[o] = sum_h W2[h,o]  (precomputed f32).
//
// ws: W1T f16 [1024][1024] @0 (2MiB) | W2T f16 [128][1024] @2MiB (256KiB)
//     Ep f16 [2048][1024] @2.25MiB (4MiB) | Dp f16 [512][1024] @6.25MiB (1MiB)
//     Csum f32 [128] @7.25MiB

typedef _Float16 f16x8 __attribute__((ext_vector_type(8)));
typedef _Float16 f16x2 __attribute__((ext_vector_type(2)));
typedef float    f32x4 __attribute__((ext_vector_type(4)));

#define C2L 2.8853900817779268f

__device__ __forceinline__ float fast_exp2(float x) { return __builtin_amdgcn_exp2f(x); }

// v_cvt_pkrtz_f16_f32 returns __fp16x2 — bitcast to our _Float16x2
__device__ __forceinline__ f16x2 pk_cvt(float x, float y) {
    auto r = __builtin_amdgcn_cvt_pkrtz(x, y);
    union { decltype(r) a; f16x2 b; } c; c.a = r; return c.b;
}

// r = 1/(e*d + 1) on 8 packed f16 via pairwise reciprocal (4 rcph per 8).
// p capped at 126 so q = p0*p1 <= 15876 keeps rq = rcph(q) >= 6.3e-5 in the
// f16 normal range. The "1-2r" of tanh lives in the epilogue (Csum identity).
__device__ __forceinline__ f16x8 recip8(f16x8 e, f16x8 d) {
    const f16x8 one = {1,1,1,1,1,1,1,1};
    const f16x8 cap = {126,126,126,126,126,126,126,126};
    union { f16x8 v; _Float16 s[8]; } p, r;
    p.v = e * d + one;                              // v_pk_fma_f16 x4
    p.v = __builtin_elementwise_min(p.v, cap);      // v_pk_min_f16 x4
    #pragma unroll
    for (int i = 0; i < 4; ++i) {
        _Float16 q  = p.s[2*i] * p.s[2*i+1];
        _Float16 rq = __builtin_amdgcn_rcph(q);
        r.s[2*i]   = p.s[2*i+1] * rq;               // = 1/p0
        r.s[2*i+1] = p.s[2*i]   * rq;               // = 1/p1
    }
    return r.v;
}

// async 16B global -> LDS (LDS dest is wave-uniform base + lane*16)
__device__ __forceinline__ void stage16(const void* g, void* l) {
    __builtin_amdgcn_global_load_lds(
        (const __attribute__((address_space(1))) unsigned int*)g,
        (__attribute__((address_space(3))) unsigned int*)l, 16, 0, 0);
}

// ---------------------------------------------------------------- transpose (+ column sums)
// bx<32: W1 (1024x1024) -> W1T ; 32<=bx<36: W2 (1024x128) -> W2T
// bx==36, by==0: Csum[o] = sum_k W2[k][o].
__global__ __launch_bounds__(1024) void transpose_both(
    const float* __restrict__ W1, const float* __restrict__ W2,
    _Float16* __restrict__ W1T, _Float16* __restrict__ W2T,
    float* __restrict__ Csum)
{
    __shared__ float tile[32][33];
    __shared__ float part[8][128];
    int bx = blockIdx.x;
    int tx = threadIdx.x, ty = threadIdx.y;
    if (bx == 36) {
        if (blockIdx.y) return;
        int t = ty * 32 + tx;            // 0..1023
        int o = t & 127, kg = t >> 7;    // 8 k-groups x 128 cols
        float s = 0.f;
        #pragma unroll 8
        for (int k = kg; k < 1024; k += 8) s += W2[k * 128 + o];
        part[kg][o] = s;
        __syncthreads();
        if (t < 128) {
            float tot = 0.f;
            #pragma unroll
            for (int g = 0; g < 8; ++g) tot += part[g][t];
            Csum[t] = tot;
        }
        return;
    }
    const float* src; _Float16* dst; int C, c0;
    if (bx < 32) { src = W1; dst = W1T; C = 1024; c0 = bx * 32; }
    else         { src = W2; dst = W2T; C = 128;  c0 = (bx - 32) * 32; }
    int r0 = blockIdx.y * 32;
    tile[ty][tx] = src[(r0 + ty) * C + (c0 + tx)];
    __syncthreads();
    dst[(size_t)(c0 + ty) * 1024 + (r0 + tx)] = (_Float16)tile[tx][ty];
}

// ---------------------------------------------------------------- projections
// rows 0..2047 -> Ep = 2^(C2L*(enc@W1[:512] + b1)); rows 2048.. -> Dp (dec, no bias)
// v3 structure exactly as R4 (best total, 138.4): 64x64 tile per block, W1T
// panel staged to LDS via global_load_lds, double-buffered BK=64, one barrier
// per tile; XOR chunk swizzle (0 bank conflicts); A rows prefetched one full
// tile deep. launch_bounds back to (256,2) — the (256,4) variant (R8/R10)
// tracked a +4 us residual.
__global__ __launch_bounds__(256, 2) void proj_exp(
    const float* __restrict__ enc,     // [2048][512]
    const float* __restrict__ dec,     // [512][512]
    const _Float16* __restrict__ W1T,  // [1024][1024]
    const float* __restrict__ b1,      // [1024]
    _Float16* __restrict__ Ep,         // [2048][1024]
    _Float16* __restrict__ Dp)         // [512][1024]
{
    __shared__ _Float16 sB[2][64 * 64];   // 2 x 8 KiB: [n-col][k] swizzled

    const int K = 512;
    int tid  = threadIdx.x;
    int w    = tid >> 6, lane = tid & 63;
    int quad = lane >> 4, l15 = lane & 15;
    int m_base = blockIdx.y * 64;
    int n_base = blockIdx.x * 64;

    bool is_enc = (m_base < 2048);          // block-uniform (boundary 2048 = 32*64)
    int row = m_base + w * 16 + l15;
    const float* A = is_enc ? (enc + (size_t)row * K)
                            : (dec + (size_t)(row - 2048) * K);
    const _Float16* Bsrc = W1T + (is_enc ? 0 : 512);

    f32x4 acc[4] = {};

    // stage B tile 0 (64 cols x 64 k f16 = 8 KiB): 512 chunks of 16B, 2/thread
    #pragma unroll
    for (int i = 0; i < 2; ++i) {
        int c = i * 256 + tid;
        int r = c >> 3, kcs = c & 7;
        stage16(Bsrc + (size_t)(n_base + r) * 1024 + ((kcs ^ (r & 7)) << 3),
                &sB[0][(i * 256 + (tid & 0xC0)) * 8]);
    }
    // A prefetch for tile 0: lane's 16 floats at k = quad*8 (+32)
    float4 a0lo = *reinterpret_cast<const float4*>(A + quad * 8);
    float4 a0hi = *reinterpret_cast<const float4*>(A + quad * 8 + 4);
    float4 a1lo = *reinterpret_cast<const float4*>(A + 32 + quad * 8);
    float4 a1hi = *reinterpret_cast<const float4*>(A + 32 + quad * 8 + 4);

    for (int it = 0; it < 8; ++it) {
        __syncthreads();   // drains stage(it) — issued one full tile ago
        float4 n0lo, n0hi, n1lo, n1hi;
        if (it < 7) {
            int kb = (it + 1) * 64;
            _Float16* dst = sB[(it + 1) & 1];
            #pragma unroll
            for (int i = 0; i < 2; ++i) {
                int c = i * 256 + tid;
                int r = c >> 3, kcs = c & 7;
                stage16(Bsrc + (size_t)(n_base + r) * 1024 + kb + ((kcs ^ (r & 7)) << 3),
                        dst + (i * 256 + (tid & 0xC0)) * 8);
            }
            n0lo = *reinterpret_cast<const float4*>(A + kb + quad * 8);
            n0hi = *reinterpret_cast<const float4*>(A + kb + quad * 8 + 4);
            n1lo = *reinterpret_cast<const float4*>(A + kb + 32 + quad * 8);
            n1hi = *reinterpret_cast<const float4*>(A + kb + 32 + quad * 8 + 4);
        }
        const _Float16* sb = sB[it & 1];
        // ki2 = 0
        {
            union { f16x8 v; f16x2 h[4]; } a;
            a.h[0] = pk_cvt(a0lo.x, a0lo.y);
            a.h[1] = pk_cvt(a0lo.z, a0lo.w);
            a.h[2] = pk_cvt(a0hi.x, a0hi.y);
            a.h[3] = pk_cvt(a0hi.z, a0hi.w);
            int sw = ((0 * 4 + quad) ^ (l15 & 7)) << 3;
            #pragma unroll
            for (int f = 0; f < 4; ++f) {
                f16x8 bb = *reinterpret_cast<const f16x8*>(sb + (f * 16 + l15) * 64 + sw);
                acc[f] = __builtin_amdgcn_mfma_f32_16x16x32_f16(a.v, bb, acc[f], 0, 0, 0);
            }
        }
        // ki2 = 1
        {
            union { f16x8 v; f16x2 h[4]; } a;
            a.h[0] = pk_cvt(a1lo.x, a1lo.y);
            a.h[1] = pk_cvt(a1lo.z, a1lo.w);
            a.h[2] = pk_cvt(a1hi.x, a1hi.y);
            a.h[3] = pk_cvt(a1hi.z, a1hi.w);
            int sw = ((1 * 4 + quad) ^ (l15 & 7)) << 3;
            #pragma unroll
            for (int f = 0; f < 4; ++f) {
                f16x8 bb = *reinterpret_cast<const f16x8*>(sb + (f * 16 + l15) * 64 + sw);
                acc[f] = __builtin_amdgcn_mfma_f32_16x16x32_f16(a.v, bb, acc[f], 0, 0, 0);
            }
        }
        a0lo = n0lo; a0hi = n0hi; a1lo = n1lo; a1hi = n1hi;
    }

    #pragma unroll
    for (int f = 0; f < 4; ++f) {
        int col = n_base + f * 16 + l15;
        float bv = is_enc ? b1[col] : 0.0f;
        #pragma unroll
        for (int v = 0; v < 4; ++v) {
            int orow = m_base + w * 16 + quad * 4 + v;
            float val = fast_exp2(C2L * (acc[f][v] + bv));
            if (is_enc) Ep[(size_t)orow * 1024 + col] = (_Float16)val;
            else        Dp[(size_t)(orow - 2048) * 1024 + col] = (_Float16)val;
        }
    }
}

// ---------------------------------------------------------------- main fused
// R8 base (best measured, 47.8 us): block = 4t x 64u x 128o, 4 waves, wave w
// owns u-rows [16w,16w+16) for all 4t; 2 independent in-phase blocks/CU
// (R5/R6/R7/R9/R10 all refuted departures: no-LDS W2T, 8-wave split, rot x2,
// 512-merge, BK=128). W2T LDS-staged BK=64 dbuf (0 bank conflicts), Ep
// staged once, Dp direct global, Csum identity epilogue.
// R11: s_setprio(1) around each ki2's MFMA cluster (T5, isolated for the
// first time — R2 bundled it inside a net-regression). Mechanism: 2
// independent blocks/CU at slightly different phases; priority lets the
// MFMA-entering wave win SIMD arbitration over the other block's staging
// wave. Zero traffic/register cost; null -> joint unchanged.
__global__ __launch_bounds__(256, 2) void joint_main(
    const _Float16* __restrict__ Ep,   // [2048][1024]
    const _Float16* __restrict__ Dp,   // [512][1024]
    const _Float16* __restrict__ W2T,  // [128][1024]
    const float* __restrict__ b2,      // [128]
    const float* __restrict__ Csum,    // [128]
    float* __restrict__ out)           // [8][256][64][128]
{
    __shared__ _Float16 sB[2][128 * 64];   // 2 x 16 KiB
    __shared__ _Float16 sE[4 * 1024];      // 8 KiB: 4 Ep rows

    int t0 = blockIdx.x * 4, b = blockIdx.y;
    int tid  = threadIdx.x;
    int w    = tid >> 6, lane = tid & 63;
    int quad = lane >> 4, l15 = lane & 15;
    int u0   = w * 16;

    const _Float16* epB = Ep + (size_t)(b * 256 + t0) * 1024;   // 4 contiguous rows
    const _Float16* dpr = Dp + (size_t)(b * 64 + u0 + l15) * 1024;

    f32x4 acc[4][8] = {};   // [t][o-tile] = 128 AGPRs

    // stage 4 Ep rows (8 KiB, linear both sides): 512 chunks, 2 per thread
    #pragma unroll
    for (int i = 0; i < 2; ++i) {
        int c = i * 256 + tid;
        stage16(epB + c * 8, sE + (i * 256 + (tid & 0xC0)) * 8);
    }
    // stage W2T tile 0 into buf 0 (1024 chunks of 16B, 4 per thread)
    #pragma unroll
    for (int i = 0; i < 4; ++i) {
        int c = i * 256 + tid;
        int row = c >> 3, kcs = c & 7;
        stage16(W2T + row * 1024 + ((kcs ^ (row & 7)) << 3),
                &sB[0][(i * 256 + (tid & 0xC0)) * 8]);
    }

    for (int it = 0; it < 16; ++it) {
        __syncthreads();   // drains stage(it) — issued one full tile ago (and sE at it=0)
        if (it < 15) {
            int kb = (it + 1) * 64;
            _Float16* dst = sB[(it + 1) & 1];
            #pragma unroll
            for (int i = 0; i < 4; ++i) {
                int c = i * 256 + tid;
                int row = c >> 3, kcs = c & 7;
                stage16(W2T + row * 1024 + kb + ((kcs ^ (row & 7)) << 3),
                        dst + (i * 256 + (tid & 0xC0)) * 8);
            }
        }
        const _Float16* sb = sB[it & 1];
        #pragma unroll
        for (int ki2 = 0; ki2 < 2; ++ki2) {
            int k = it * 64 + ki2 * 32 + quad * 8;
            f16x8 d8 = *reinterpret_cast<const f16x8*>(dpr + k);
            f16x8 A[4];
            #pragma unroll
            for (int tt = 0; tt < 4; ++tt) {
                // broadcast ds_read_b128 (same addr per quad group): conflict-free
                f16x8 e = *reinterpret_cast<const f16x8*>(sE + tt * 1024 + k);
                A[tt] = recip8(e, d8);
            }
            int kc3 = ki2 * 4 + quad;
            int sw  = (kc3 ^ (l15 & 7)) << 3;        // uniform across f
            __builtin_amdgcn_s_setprio(1);
            #pragma unroll
            for (int f = 0; f < 8; ++f) {
                f16x8 bb = *reinterpret_cast<const f16x8*>(
                    sb + (f * 16 + l15) * 64 + sw);
                #pragma unroll
                for (int tt = 0; tt < 4; ++tt)
                    acc[tt][f] = __builtin_amdgcn_mfma_f32_16x16x32_f16(A[tt], bb, acc[tt][f], 0, 0, 0);
            }
            __builtin_amdgcn_s_setprio(0);
        }
    }

    #pragma unroll
    for (int tt = 0; tt < 4; ++tt) {
        float* o = out + (size_t)(b * 256 + t0 + tt) * 64 * 128;
        #pragma unroll
        for (int f = 0; f < 8; ++f) {
            int oc = f * 16 + l15;
            float bv = Csum[oc] + b2[oc];
            #pragma unroll
            for (int v = 0; v < 4; ++v) {
                int u = u0 + quad * 4 + v;
                o[u * 128 + oc] = fmaf(-2.0f, acc[tt][f][v], bv);
            }
        }
    }
}

// ---------------------------------------------------------------- launch
extern "C" void kernel_launch(void* const* d_in, const int* in_sizes, int n_in,
                              void* d_out, int out_size, void* d_ws, size_t ws_size,
                              hipStream_t stream) {
    const float* enc = (const float*)d_in[0]; // [8][256][512]
    const float* dec = (const float*)d_in[1]; // [8][64][512]
    const float* W1  = (const float*)d_in[2]; // [1024][1024]
    const float* b1  = (const float*)d_in[3]; // [1024]
    const float* W2  = (const float*)d_in[4]; // [1024][128]
    const float* b2  = (const float*)d_in[5]; // [128]
    float* out = (float*)d_out;

    char* ws = (char*)d_ws;
    _Float16* W1T = (_Float16*)(ws);                               // 2 MiB
    _Float16* W2T = (_Float16*)(ws + (2u << 20));                  // 256 KiB
    _Float16* EpP = (_Float16*)(ws + (2u << 20) + (256u << 10));   // 4 MiB
    _Float16* DpP = (_Float16*)(ws + (6u << 20) + (256u << 10));   // 1 MiB
    float*    Csm = (float*)   (ws + (7u << 20) + (256u << 10));   // 512 B

    transpose_both<<<dim3(37, 32), dim3(32, 32), 0, stream>>>(W1, W2, W1T, W2T, Csm);

    // fused projections + exp2 epilogue: M = 2048 (enc) + 512 (dec)
    proj_exp<<<dim3(16, 40), 256, 0, stream>>>(enc, dec, W1T, b1, EpP, DpP);

    joint_main<<<dim3(64, 8), 256, 0, stream>>>(EpP, DpP, W2T, b2, Csm, out);
}